// Round 5
// baseline (73.012 us; speedup 1.0000x reference)
//
#include <hip/hip_runtime.h>

// Chamfer distance v2: B=4, N=M=4096, D=3, fp32 in, scalar fp32 out.
//
// R5 = R4 skeleton (2 dispatches, 1024 blocks = 4/CU, chunked LDS
// double-buffer, |h|^2 folded out of the inner loop) + G=8->16:
// a phase-group now spans 2 waves (PHN=128, 2 groups/block, G=16), so each
// ds_read_b128 stream point serves 16 held points instead of 8 -> LDS pipe
// demand halves (~83% -> ~43% of VALU time) while per-pair VALU stays at the
// 3.5-op floor (3 fma/pt + v_min3 per 2 pts). ~105 VGPR, still 4 blocks/CU.
// Cross-wave phase min handled once in epilogue via 4x16 LDS.

#define NPTS 4096
#define TILE 32     // held points per block
#define PHN  128    // phases = threads per held-group (2 waves)
#define G    16     // held points per thread
#define CH   512    // stream chunk
#define NCH  8      // NPTS / CH

__global__ __launch_bounds__(256, 4) void chamfer_pass(
    const float* __restrict__ coord, const float* __restrict__ gt,
    float* __restrict__ partials)
{
    __shared__ float4 sc[2][CH];   // 16 KB
    __shared__ float red[4][16];   // per-wave phase-reduced mins
    __shared__ float bsum[2];

    int bx   = blockIdx.x;
    int pass = bx >> 9;            // 0: held=gt/stream=coord, 1: reverse
    int r    = bx & 511;
    int b    = r >> 7;
    int tile = r & 127;            // 128 tiles of 32 held pts

    const float* hbase = (pass ? coord : gt) + b * NPTS * 3;
    const float* sbase = (pass ? gt : coord) + b * NPTS * 3;

    int tid = threadIdx.x;
    int hg  = tid >> 7;            // 0..1 held group (2 waves each)
    int ph  = tid & 127;           // 0..127 phase
    int w   = tid >> 6;            // 0..3 wave id

    // ---- held points -> registers (identical across the group's 2 waves) ----
    float hx[G], hy[G], hz[G], h2[G], mn[G];
    int h0 = tile * TILE + hg * G;
#pragma unroll
    for (int g = 0; g < G; ++g) {
        float x = hbase[(h0 + g) * 3 + 0];
        float y = hbase[(h0 + g) * 3 + 1];
        float z = hbase[(h0 + g) * 3 + 2];
        hx[g] = x; hy[g] = y; hz[g] = z;
        h2[g] = x * x + y * y + z * z;
        mn[g] = INFINITY;
    }

    // ---- stage chunk 0: (-2x,-2y,-2z,|c|^2) ----
    {
        int p = tid * 2;
        const float* s0 = sbase + p * 3;
        float x0 = s0[0], y0 = s0[1], z0 = s0[2];
        float x1 = s0[3], y1 = s0[4], z1 = s0[5];
        sc[0][p]     = make_float4(-2.f*x0, -2.f*y0, -2.f*z0, x0*x0 + y0*y0 + z0*z0);
        sc[0][p + 1] = make_float4(-2.f*x1, -2.f*y1, -2.f*z1, x1*x1 + y1*y1 + z1*z1);
    }
    __syncthreads();

    for (int ch = 0; ch < NCH; ++ch) {
        if (ch + 1 < NCH) {        // prefetch next chunk into other buffer
            int p = tid * 2;
            const float* s0 = sbase + ((ch + 1) * CH + p) * 3;
            float x0 = s0[0], y0 = s0[1], z0 = s0[2];
            float x1 = s0[3], y1 = s0[4], z1 = s0[5];
            int nb = (ch + 1) & 1;
            sc[nb][p]     = make_float4(-2.f*x0, -2.f*y0, -2.f*z0, x0*x0 + y0*y0 + z0*z0);
            sc[nb][p + 1] = make_float4(-2.f*x1, -2.f*y1, -2.f*z1, x1*x1 + y1*y1 + z1*z1);
        }

        const float4* cur = sc[ch & 1];
#pragma unroll
        for (int it = 0; it < CH / (2 * PHN); ++it) {   // 2 iters
            float4 c0 = cur[it * 256 + ph];
            float4 c1 = cur[it * 256 + 128 + ph];
#pragma unroll
            for (int g = 0; g < G; ++g) {
                float a = fmaf(c0.x, hx[g], c0.w);       // |c|^2 - 2 c.h
                a = fmaf(c0.y, hy[g], a);
                a = fmaf(c0.z, hz[g], a);
                float d = fmaf(c1.x, hx[g], c1.w);
                d = fmaf(c1.y, hy[g], d);
                d = fmaf(c1.z, hz[g], d);
                mn[g] = fminf(fminf(a, d), mn[g]);        // v_min3_f32
            }
        }
        __syncthreads();
    }

    // ---- min over 64 lanes within each wave ----
#pragma unroll
    for (int g = 0; g < G; ++g) {
        float v = mn[g];
        v = fminf(v, __shfl_xor(v, 32));
        v = fminf(v, __shfl_xor(v, 16));
        v = fminf(v, __shfl_xor(v, 8));
        v = fminf(v, __shfl_xor(v, 4));
        v = fminf(v, __shfl_xor(v, 2));
        v = fminf(v, __shfl_xor(v, 1));
        mn[g] = v;
    }
    if ((tid & 63) == 0) {
#pragma unroll
        for (int g = 0; g < G; ++g) red[w][g] = mn[g];
    }
    __syncthreads();

    // ---- combine the group's 2 waves, add h2, clamp, sum over g ----
    if ((tid & 127) == 0) {        // tid 0 (group 0) and 128 (group 1)
        int w0 = hg * 2;
        float s = 0.f;
#pragma unroll
        for (int g = 0; g < G; ++g)
            s += fmaxf(fminf(red[w0][g], red[w0 + 1][g]) + h2[g], 0.f);
        bsum[hg] = s;
    }
    __syncthreads();
    if (tid == 0)
        partials[bx] = bsum[0] + bsum[1];
}

__global__ __launch_bounds__(256) void chamfer_final(
    const float* __restrict__ partials, float* __restrict__ out)
{
    __shared__ float wsum[4];
    int tid = threadIdx.x;
    float s = 0.f;
#pragma unroll
    for (int k = 0; k < 4; ++k)
        s += partials[k * 256 + tid];
#pragma unroll
    for (int off = 32; off > 0; off >>= 1)
        s += __shfl_down(s, off);
    if ((tid & 63) == 0) wsum[tid >> 6] = s;
    __syncthreads();
    if (tid == 0)
        out[0] = (wsum[0] + wsum[1] + wsum[2] + wsum[3]) * (1.0f / 16384.0f);
}

extern "C" void kernel_launch(void* const* d_in, const int* in_sizes, int n_in,
                              void* d_out, int out_size, void* d_ws, size_t ws_size,
                              hipStream_t stream) {
    const float* coord = (const float*)d_in[0];  // [4,4096,3]
    const float* gt    = (const float*)d_in[1];  // [4,4096,3]
    float* partials = (float*)d_ws;              // 1024 floats
    float* out = (float*)d_out;

    chamfer_pass<<<1024, 256, 0, stream>>>(coord, gt, partials);
    chamfer_final<<<1, 256, 0, stream>>>(partials, out);
}

// Round 6
// 71.248 us; speedup vs baseline: 1.0248x; 1.0248x over previous
//
#include <hip/hip_runtime.h>

// Chamfer distance v2: B=4, N=M=4096, D=3, fp32 in, scalar fp32 out.
//
// R6 = revert to R4 (measured best, 70.5 us). Departures from this structure
// all regressed: R1 atomic-combine (72.1), R3 fused single-dispatch (76.2),
// R5 G=16 two-wave groups (73.0 — 80-VGPR held arrays under the 128 cap
// killed staging/inner ILP). Keep: 2 dispatches, 1024 blocks = 4/CU,
// chunked LDS double-buffer, |h|^2 folded out of the inner loop
// (min_c d2 = h2 + min_c(|c|^2 - 2 c.h)), G=8, PHN=64, 4-deep inner unroll.
// Inner loop = 3 fma/pt + v_min3 per 2 pts = 3.5 VALU/pair (~6 us floor).
//
// Timed-window budget (R1-R5 profiles): ~40 us harness ws re-poison fill
// (268 MB @ 85% HBM peak) + ~18-20 us restores/gaps (fixed) + ~10.5 us mine.

#define NPTS 4096
#define TILE 32     // held points per block
#define PHN  64     // phases = threads per held-group (full wave)
#define G    8      // held points per thread
#define CH   512    // stream chunk
#define NCH  8      // NPTS / CH

__global__ __launch_bounds__(256, 4) void chamfer_pass(
    const float* __restrict__ coord, const float* __restrict__ gt,
    float* __restrict__ partials)
{
    __shared__ float4 sc[2][CH];   // 16 KB
    __shared__ float bsum[4];

    int bx   = blockIdx.x;
    int pass = bx >> 9;            // 0: held=gt/stream=coord, 1: reverse
    int r    = bx & 511;
    int b    = r >> 7;
    int tile = r & 127;            // 128 tiles of 32 held pts

    const float* hbase = (pass ? coord : gt) + b * NPTS * 3;
    const float* sbase = (pass ? gt : coord) + b * NPTS * 3;

    int tid = threadIdx.x;
    int hg  = tid >> 6;            // 0..3 held group
    int ph  = tid & 63;            // 0..63 phase (full wave)

    // ---- held points -> registers (broadcast across the wave) ----
    float hx[G], hy[G], hz[G], h2[G], mn[G];
    int h0 = tile * TILE + hg * G;
#pragma unroll
    for (int g = 0; g < G; ++g) {
        float x = hbase[(h0 + g) * 3 + 0];
        float y = hbase[(h0 + g) * 3 + 1];
        float z = hbase[(h0 + g) * 3 + 2];
        hx[g] = x; hy[g] = y; hz[g] = z;
        h2[g] = x * x + y * y + z * z;
        mn[g] = INFINITY;
    }

    // ---- stage chunk 0: (-2x,-2y,-2z,|c|^2) ----
    {
        int p = tid * 2;
        const float* s0 = sbase + p * 3;
        float x0 = s0[0], y0 = s0[1], z0 = s0[2];
        float x1 = s0[3], y1 = s0[4], z1 = s0[5];
        sc[0][p]     = make_float4(-2.f*x0, -2.f*y0, -2.f*z0, x0*x0 + y0*y0 + z0*z0);
        sc[0][p + 1] = make_float4(-2.f*x1, -2.f*y1, -2.f*z1, x1*x1 + y1*y1 + z1*z1);
    }
    __syncthreads();

    for (int ch = 0; ch < NCH; ++ch) {
        if (ch + 1 < NCH) {        // prefetch next chunk into other buffer
            int p = tid * 2;
            const float* s0 = sbase + ((ch + 1) * CH + p) * 3;
            float x0 = s0[0], y0 = s0[1], z0 = s0[2];
            float x1 = s0[3], y1 = s0[4], z1 = s0[5];
            int nb = (ch + 1) & 1;
            sc[nb][p]     = make_float4(-2.f*x0, -2.f*y0, -2.f*z0, x0*x0 + y0*y0 + z0*z0);
            sc[nb][p + 1] = make_float4(-2.f*x1, -2.f*y1, -2.f*z1, x1*x1 + y1*y1 + z1*z1);
        }

        const float4* cur = sc[ch & 1];
#pragma unroll
        for (int it = 0; it < CH / (2 * PHN); ++it) {   // 4 iters
            float4 c0 = cur[it * 128 + ph];
            float4 c1 = cur[it * 128 + 64 + ph];
#pragma unroll
            for (int g = 0; g < G; ++g) {
                float a = fmaf(c0.x, hx[g], c0.w);       // |c|^2 - 2 c.h
                a = fmaf(c0.y, hy[g], a);
                a = fmaf(c0.z, hz[g], a);
                float d = fmaf(c1.x, hx[g], c1.w);
                d = fmaf(c1.y, hy[g], d);
                d = fmaf(c1.z, hz[g], d);
                mn[g] = fminf(fminf(a, d), mn[g]);        // v_min3_f32
            }
        }
        __syncthreads();
    }

    // ---- min over 64 phases, add h2, sum over g ----
    float s = 0.f;
#pragma unroll
    for (int g = 0; g < G; ++g) {
        float v = mn[g];
        v = fminf(v, __shfl_xor(v, 32));
        v = fminf(v, __shfl_xor(v, 16));
        v = fminf(v, __shfl_xor(v, 8));
        v = fminf(v, __shfl_xor(v, 4));
        v = fminf(v, __shfl_xor(v, 2));
        v = fminf(v, __shfl_xor(v, 1));
        s += fmaxf(v + h2[g], 0.f);   // true d^2 >= 0; clamp fp cancellation
    }
    if (ph == 0) bsum[hg] = s;
    __syncthreads();
    if (tid == 0)
        partials[bx] = bsum[0] + bsum[1] + bsum[2] + bsum[3];
}

__global__ __launch_bounds__(256) void chamfer_final(
    const float* __restrict__ partials, float* __restrict__ out)
{
    __shared__ float wsum[4];
    int tid = threadIdx.x;
    float s = 0.f;
#pragma unroll
    for (int k = 0; k < 4; ++k)
        s += partials[k * 256 + tid];
#pragma unroll
    for (int off = 32; off > 0; off >>= 1)
        s += __shfl_down(s, off);
    if ((tid & 63) == 0) wsum[tid >> 6] = s;
    __syncthreads();
    if (tid == 0)
        out[0] = (wsum[0] + wsum[1] + wsum[2] + wsum[3]) * (1.0f / 16384.0f);
}

extern "C" void kernel_launch(void* const* d_in, const int* in_sizes, int n_in,
                              void* d_out, int out_size, void* d_ws, size_t ws_size,
                              hipStream_t stream) {
    const float* coord = (const float*)d_in[0];  // [4,4096,3]
    const float* gt    = (const float*)d_in[1];  // [4,4096,3]
    float* partials = (float*)d_ws;              // 1024 floats
    float* out = (float*)d_out;

    chamfer_pass<<<1024, 256, 0, stream>>>(coord, gt, partials);
    chamfer_final<<<1, 256, 0, stream>>>(partials, out);
}